// Round 4
// baseline (413.482 us; speedup 1.0000x reference)
//
#include <hip/hip_runtime.h>
#include <hip/hip_bf16.h>
#include <stdint.h>

#define NN 131072

typedef unsigned int uint;
typedef unsigned short ushort;
typedef __attribute__((ext_vector_type(8))) __bf16 bf16x8;
typedef __attribute__((ext_vector_type(2))) __bf16 bf16x2;
typedef __attribute__((ext_vector_type(4))) float f32x4;

// ---------------- ws layout (bytes) ----------------
// [512K,1M)  Bt  (256 x 1024 bf16: Bt[c][k])
// 1M         cf (256 f32); 1M+1024 flag; 1M+2048 scale; 1M+3072 shift
// [2M,3M)    bn_s (1024*256 f32)
// [4M,5M)    bn_q
// [8M,+64M)  graph_feats bf16 (NN*256)

__device__ __forceinline__ ushort f2bf(float f) {
    uint u = __float_as_uint(f);
    u += 0x7FFF + ((u >> 16) & 1);
    return (ushort)(u >> 16);
}
__device__ __forceinline__ uint pk2(float a, float b) {
    bf16x2 t;
    t[0] = (__bf16)a;
    t[1] = (__bf16)b;
    return __builtin_bit_cast(uint, t);
}
__device__ __forceinline__ bool mask_val(const unsigned char* m8, int flag, int i) {
    return flag ? (m8[(size_t)i * 4] != 0) : (m8[i] != 0);
}

// Detect whether mask buffer is 1-byte bool (flag=0) or int32 (flag=1).
__global__ void k_detect(const unsigned char* m8, int n, int* flag) {
    __shared__ int cnt;
    if (threadIdx.x == 0) cnt = 0;
    __syncthreads();
    int local = 0;
    for (int i = threadIdx.x * 4 + 1; i < n; i += 1024) local += (m8[i] != 0) ? 1 : 0;
    if (local) atomicAdd(&cnt, local);
    __syncthreads();
    if (threadIdx.x == 0) *flag = (cnt == 0) ? 1 : 0;
}

// Build Bt[c][k] (bf16): k<256 -> W_a[k][c]; 256..511 -> W_f[k-256][c];
// 512..1023 -> (W_v @ W_f_bot)[k-512][c].  Block 1024 computes c_f.
__global__ void k_prep(const float* __restrict__ Wa, const float* __restrict__ Wf,
                       const float* __restrict__ Wv, const float* __restrict__ bv,
                       const float* __restrict__ bf_, ushort* __restrict__ Bt,
                       float* __restrict__ cf) {
    int c = threadIdx.x;
    int b = blockIdx.x;
    if (b < 256) {
        Bt[(size_t)c * 1024 + b] = f2bf(Wa[b * 256 + c]);
    } else if (b < 512) {
        Bt[(size_t)c * 1024 + b] = f2bf(Wf[(b - 256) * 256 + c]);
    } else if (b < 1024) {
        const float* wr = Wv + (b - 512) * 256;
        float acc = 0.f;
        for (int j = 0; j < 256; ++j) acc += wr[j] * Wf[(256 + j) * 256 + c];
        Bt[(size_t)c * 1024 + b] = f2bf(acc);
    } else {
        float acc = bf_[c];
        for (int j = 0; j < 256; ++j) acc += bv[j] * Wf[(256 + j) * 256 + c];
        cf[c] = acc;
    }
}

// Fused: cosine-sim prologue + MFMA GEMM (BM=128, BN=256, K=1024 virtual,
// BK=64, 8 waves 2x4). A double-buffered in LDS (1 barrier/step); B-fragments
// loaded directly from L2-resident Bt. Writes bf16 gf + BN partials.
__global__ __launch_bounds__(512, 4) void k_main(
    const float* __restrict__ x, const unsigned char* __restrict__ m8,
    const int* __restrict__ flagp, const ushort* __restrict__ Bt,
    const float* __restrict__ ba, const float* __restrict__ cf,
    ushort* __restrict__ gf, float* __restrict__ bn_s, float* __restrict__ bn_q)
{
    __shared__ bf16x8 As8[2][128 * 8];        // 2 x 16 KB
    __shared__ float simS[128];
    __shared__ unsigned char maskS[128];
    __shared__ float redS[256], redQ[256];

    const int tid = threadIdx.x;
    const int flag = *flagp;
    const int rowBase = blockIdx.x * 128;
    const int lane = tid & 63;
    const int w = tid >> 6, wr = w >> 2, wc = w & 3;
    const int fr = lane & 15, fg = lane >> 4;

    if (tid < 128) maskS[tid] = mask_val(m8, flag, rowBase + tid) ? 1 : 0;

    // ---- phase 1: cosine sim, wave-per-row (fully coalesced 1KB loads) ----
    #pragma unroll 2
    for (int rr = 0; rr < 16; ++rr) {
        int r = w * 16 + rr;
        const float4* p = (const float4*)(x + (size_t)(rowBase + r) * 2048 + 1024);
        float4 a0 = p[lane], a1 = p[lane + 64];
        float4 v0 = p[lane + 128], v1 = p[lane + 192];
        float dot = a0.x * v0.x + a0.y * v0.y + a0.z * v0.z + a0.w * v0.w
                  + a1.x * v1.x + a1.y * v1.y + a1.z * v1.z + a1.w * v1.w;
        float na = a0.x * a0.x + a0.y * a0.y + a0.z * a0.z + a0.w * a0.w
                 + a1.x * a1.x + a1.y * a1.y + a1.z * a1.z + a1.w * a1.w;
        float nv = v0.x * v0.x + v0.y * v0.y + v0.z * v0.z + v0.w * v0.w
                 + v1.x * v1.x + v1.y * v1.y + v1.z * v1.z + v1.w * v1.w;
        #pragma unroll
        for (int off = 32; off; off >>= 1) {
            dot += __shfl_xor(dot, off);
            na  += __shfl_xor(na,  off);
            nv  += __shfl_xor(nv,  off);
        }
        if (lane == 0)
            simS[r] = dot / fmaxf(sqrtf(na) * sqrtf(nv), 1e-8f);
    }
    __syncthreads();

    // ---- phase 2: GEMM ----
    const int sr = tid >> 2, sk = tid & 3;
    const float* xrow = x + (size_t)(rowBase + sr) * 2048;
    const int msk_s = maskS[sr];
    const float sims = simS[sr];
    const float scl0 = msk_s ? 1.f : 0.f;
    const float scl1 = msk_s ? 0.f : sims;
    const float scl2 = msk_s ? 0.f : 1.f;

    // per-lane B base: col = wc*64 + fr (n adds n*16 cols), k-fine = fg*8
    const ushort* bB = Bt + (size_t)(wc * 64 + fr) * 1024 + fg * 8;

    f32x4 acc[4][4];
    #pragma unroll
    for (int m = 0; m < 4; ++m)
        #pragma unroll
        for (int n = 0; n < 4; ++n) acc[m][n] = (f32x4){0.f, 0.f, 0.f, 0.f};

    int4 pA[2];
    auto loadA = [&](int st) {
        const int k0 = st * 64;
        const float scl = (st < 4) ? scl0 : (st < 8) ? scl1 : scl2;
        const float4* src = (const float4*)(xrow + ((st < 8) ? (k0 & 255) : k0) + sk * 16);
        #pragma unroll
        for (int s = 0; s < 2; ++s) {
            float4 u0 = src[2 * s], u1 = src[2 * s + 1];
            int4 p;
            p.x = pk2(u0.x * scl, u0.y * scl);
            p.y = pk2(u0.z * scl, u0.w * scl);
            p.z = pk2(u1.x * scl, u1.y * scl);
            p.w = pk2(u1.z * scl, u1.w * scl);
            pA[s] = p;
        }
    };
    auto storeA = [&](int buf) {
        #pragma unroll
        for (int s = 0; s < 2; ++s)
            As8[buf][sr * 8 + ((sk * 2 + s) ^ (sr & 7))] = __builtin_bit_cast(bf16x8, pA[s]);
    };

    // step order: interleave seg0/seg1 so the a_in re-read L2-hits
    const int STEPS[16] = {0, 4, 1, 5, 2, 6, 3, 7, 8, 9, 10, 11, 12, 13, 14, 15};

    loadA(STEPS[0]);
    storeA(0);
    __syncthreads();

    #pragma unroll
    for (int ii = 0; ii < 16; ++ii) {
        const int st = STEPS[ii];
        if (ii < 15) loadA(STEPS[ii + 1]);
        #pragma unroll
        for (int kk = 0; kk < 2; ++kk) {
            // B-fragments straight from L2-resident Bt
            bf16x8 bv[4];
            #pragma unroll
            for (int n = 0; n < 4; ++n)
                bv[n] = *(const bf16x8*)(bB + (size_t)n * 16 * 1024 + st * 64 + kk * 32);
            bf16x8 af[4];
            #pragma unroll
            for (int m = 0; m < 4; ++m) {
                int r = wr * 64 + m * 16 + fr;
                af[m] = As8[ii & 1][r * 8 + ((kk * 4 + fg) ^ (r & 7))];
            }
            #pragma unroll
            for (int n = 0; n < 4; ++n)
                #pragma unroll
                for (int m = 0; m < 4; ++m)
                    acc[m][n] = __builtin_amdgcn_mfma_f32_16x16x32_bf16(
                        af[m], bv[n], acc[m][n], 0, 0, 0);
        }
        if (ii < 15) storeA((ii + 1) & 1);
        __syncthreads();
    }

    // ---- epilogue: bias, bf16 gf store, BN partials ----
    if (tid < 256) { redS[tid] = 0.f; redQ[tid] = 0.f; }
    __syncthreads();

    const int colLo = wc * 64 + fr;
    float baN[4], cfN[4];
    #pragma unroll
    for (int n = 0; n < 4; ++n) {
        baN[n] = ba[colLo + n * 16];
        cfN[n] = cf[colLo + n * 16];
    }
    float cs[4] = {0.f, 0.f, 0.f, 0.f}, cq[4] = {0.f, 0.f, 0.f, 0.f};
    #pragma unroll
    for (int m = 0; m < 4; ++m) {
        #pragma unroll
        for (int j = 0; j < 4; ++j) {
            int rloc = wr * 64 + m * 16 + fg * 4 + j;
            int mk = maskS[rloc];
            ushort* grow = gf + (size_t)(rowBase + rloc) * 256;
            #pragma unroll
            for (int n = 0; n < 4; ++n) {
                float g = acc[m][n][j] + (mk ? baN[n] : cfN[n]);
                grow[colLo + n * 16] = f2bf(g);
                cs[n] += g;
                cq[n] += g * g;
            }
        }
    }
    #pragma unroll
    for (int n = 0; n < 4; ++n) {
        atomicAdd(&redS[colLo + n * 16], cs[n]);
        atomicAdd(&redQ[colLo + n * 16], cq[n]);
    }
    __syncthreads();
    if (tid < 256) {
        bn_s[(size_t)blockIdx.x * 256 + tid] = redS[tid];
        bn_q[(size_t)blockIdx.x * 256 + tid] = redQ[tid];
    }
}

// Finalize BN stats: one block per channel, reduce 1024 row-block partials.
__global__ void k_stats(const float* __restrict__ bn_s, const float* __restrict__ bn_q,
                        const float* __restrict__ gamma, const float* __restrict__ beta,
                        float* __restrict__ scale, float* __restrict__ shift) {
    int c = blockIdx.x;
    int t = threadIdx.x;
    float s = 0.f, q = 0.f;
    for (int r = t; r < 1024; r += 256) {
        s += bn_s[(size_t)r * 256 + c];
        q += bn_q[(size_t)r * 256 + c];
    }
    __shared__ float ss[256], qq[256];
    ss[t] = s; qq[t] = q;
    __syncthreads();
    for (int off = 128; off; off >>= 1) {
        if (t < off) { ss[t] += ss[t + off]; qq[t] += qq[t + off]; }
        __syncthreads();
    }
    if (t == 0) {
        float mu  = ss[0] / 131072.f;
        float var = qq[0] / 131072.f - mu * mu;
        float sc = gamma[c] * rsqrtf(var + 1e-5f);
        scale[c] = sc;
        shift[c] = beta[c] - mu * sc;
    }
}

// Normalize + ReLU + 256->2 FC. One wave per row, bf16 gf input.
__global__ void k_out(const ushort* __restrict__ gf, const float* __restrict__ scale,
                      const float* __restrict__ shift, const float* __restrict__ Wfc,
                      const float* __restrict__ bfc, float* __restrict__ out) {
    int wid = threadIdx.x >> 6;
    int lane = threadIdx.x & 63;
    int i = blockIdx.x * 4 + wid;
    uint2 gv = ((const uint2*)(gf + (size_t)i * 256))[lane];
    float g0 = __uint_as_float(gv.x << 16);
    float g1 = __uint_as_float(gv.x & 0xFFFF0000u);
    float g2 = __uint_as_float(gv.y << 16);
    float g3 = __uint_as_float(gv.y & 0xFFFF0000u);
    int c0 = lane * 4;
    float4 sc = *(const float4*)(scale + c0);
    float4 sh = *(const float4*)(shift + c0);
    float y0 = fmaxf(g0 * sc.x + sh.x, 0.f);
    float y1 = fmaxf(g1 * sc.y + sh.y, 0.f);
    float y2 = fmaxf(g2 * sc.z + sh.z, 0.f);
    float y3 = fmaxf(g3 * sc.w + sh.w, 0.f);
    const float4* w = (const float4*)(Wfc + c0 * 2);
    float4 w0 = w[0], w1 = w[1];
    float p0 = y0 * w0.x + y1 * w0.z + y2 * w1.x + y3 * w1.z;
    float p1 = y0 * w0.y + y1 * w0.w + y2 * w1.y + y3 * w1.w;
    #pragma unroll
    for (int off = 32; off; off >>= 1) {
        p0 += __shfl_xor(p0, off);
        p1 += __shfl_xor(p1, off);
    }
    if (lane == 0) {
        out[(size_t)i * 2]     = p0 + bfc[0];
        out[(size_t)i * 2 + 1] = p1 + bfc[1];
    }
}

extern "C" void kernel_launch(void* const* d_in, const int* in_sizes, int n_in,
                              void* d_out, int out_size, void* d_ws, size_t ws_size,
                              hipStream_t stream) {
    const float* x          = (const float*)d_in[0];
    const unsigned char* mk = (const unsigned char*)d_in[1];
    const float* Wa  = (const float*)d_in[2];
    const float* ba  = (const float*)d_in[3];
    const float* Wv  = (const float*)d_in[4];
    const float* bv  = (const float*)d_in[5];
    const float* Wf  = (const float*)d_in[6];
    const float* bf  = (const float*)d_in[7];
    const float* gamma = (const float*)d_in[8];
    const float* beta  = (const float*)d_in[9];
    const float* Wfc = (const float*)d_in[10];
    const float* bfc = (const float*)d_in[11];
    float* out = (float*)d_out;

    char* ws = (char*)d_ws;
    ushort* Bt    = (ushort*)(ws + (512u << 10));
    float*  cf    = (float*)(ws + (1u << 20));
    int*    flag  = (int*)  (ws + (1u << 20) + 1024);
    float*  scale = (float*)(ws + (1u << 20) + 2048);
    float*  shift = (float*)(ws + (1u << 20) + 3072);
    float*  bn_s  = (float*)(ws + (2u << 20));
    float*  bn_q  = (float*)(ws + (4u << 20));
    ushort* gf    = (ushort*)(ws + (8u << 20));

    int n = in_sizes[1];  // NN

    k_detect<<<1, 256, 0, stream>>>(mk, n, flag);
    k_prep<<<1025, 256, 0, stream>>>(Wa, Wf, Wv, bv, bf, Bt, cf);
    k_main<<<1024, 512, 0, stream>>>(x, mk, flag, Bt, ba, cf, gf, bn_s, bn_q);
    k_stats<<<256, 256, 0, stream>>>(bn_s, bn_q, gamma, beta, scale, shift);
    k_out<<<NN / 4, 256, 0, stream>>>(gf, scale, shift, Wfc, bfc, out);
}

// Round 5
// 263.881 us; speedup vs baseline: 1.5669x; 1.5669x over previous
//
#include <hip/hip_runtime.h>
#include <hip/hip_bf16.h>
#include <stdint.h>

#define NN 131072

typedef unsigned int uint;
typedef unsigned short ushort;
typedef __attribute__((ext_vector_type(8))) __bf16 bf16x8;
typedef __attribute__((ext_vector_type(2))) __bf16 bf16x2;
typedef __attribute__((ext_vector_type(4))) float f32x4;

// ---------------- ws layout (bytes) ----------------
// 0: flag, 4: cntF, 8: cntA
// 1K: scale(256f), 2K: shift(256f), 3K: cf(256f)
// 8K: cntM[512], 12K: baseA[512], 16K: baseF[512]
// 32K: Bta (256x256 bf16, [c][k]) = 128KB
// 256K: Btf (256x768 bf16, [c][k]) = 384KB
// 1M: fusedIdx (512KB), 1.5M: audioIdx (512KB)
// 2M: bn_s (1025*256 f32), 4M: bn_q
// 8M: gf bf16 (NN*256)

__device__ __forceinline__ ushort f2bf(float f) {
    uint u = __float_as_uint(f);
    u += 0x7FFF + ((u >> 16) & 1);
    return (ushort)(u >> 16);
}
__device__ __forceinline__ uint pk2(float a, float b) {
    bf16x2 t;
    t[0] = (__bf16)a;
    t[1] = (__bf16)b;
    return __builtin_bit_cast(uint, t);
}
__device__ __forceinline__ bool mask_val(const unsigned char* m8, int flag, int i) {
    return flag ? (m8[(size_t)i * 4] != 0) : (m8[i] != 0);
}

// Detect whether mask buffer is 1-byte bool (flag=0) or int32 (flag=1).
__global__ void k_detect(const unsigned char* m8, int n, int* flag) {
    __shared__ int cnt;
    if (threadIdx.x == 0) cnt = 0;
    __syncthreads();
    int local = 0;
    for (int i = threadIdx.x * 4 + 1; i < n; i += 1024) local += (m8[i] != 0) ? 1 : 0;
    if (local) atomicAdd(&cnt, local);
    __syncthreads();
    if (threadIdx.x == 0) *flag = (cnt == 0) ? 1 : 0;
}

// Per-256-row-chunk audio count.
__global__ void k_count(const unsigned char* m8, const int* flagp, int* cntM) {
    int flag = *flagp;
    int t = threadIdx.x;
    bool m = mask_val(m8, flag, blockIdx.x * 256 + t);
    unsigned long long bal = __ballot(m);
    __shared__ int wsum[4];
    if ((t & 63) == 0) wsum[t >> 6] = __popcll(bal);
    __syncthreads();
    if (t == 0) cntM[blockIdx.x] = wsum[0] + wsum[1] + wsum[2] + wsum[3];
}

// Exclusive scan of chunk counts -> bases + totals. One block, 512 threads.
__global__ void k_scan(const int* __restrict__ cntM, int* __restrict__ meta,
                       int* __restrict__ baseA, int* __restrict__ baseF) {
    __shared__ int sA[512], sF[512];
    int t = threadIdx.x;
    int a = cntM[t], f = 256 - a;
    sA[t] = a; sF[t] = f;
    __syncthreads();
    for (int off = 1; off < 512; off <<= 1) {
        int va = (t >= off) ? sA[t - off] : 0;
        int vf = (t >= off) ? sF[t - off] : 0;
        __syncthreads();
        sA[t] += va; sF[t] += vf;
        __syncthreads();
    }
    baseA[t] = sA[t] - a;
    baseF[t] = sF[t] - f;
    if (t == 511) { meta[2] = sA[511]; meta[1] = sF[511]; }
}

// Stable partition fill.
__global__ void k_fill(const unsigned char* m8, const int* flagp,
                       const int* __restrict__ baseA, const int* __restrict__ baseF,
                       int* __restrict__ audioIdx, int* __restrict__ fusedIdx) {
    int flag = *flagp;
    int blk = blockIdx.x, t = threadIdx.x;
    int row = blk * 256 + t;
    bool m = mask_val(m8, flag, row);
    unsigned long long bal = __ballot(m);
    int lane = t & 63, w = t >> 6;
    unsigned long long lt = (1ull << lane) - 1ull;
    int pA = __popcll(bal & lt);
    __shared__ int wA[4];
    if (lane == 0) wA[w] = __popcll(bal);
    __syncthreads();
    int offA = 0;
    for (int i = 0; i < w; ++i) offA += wA[i];
    int offF = w * 64 - offA;
    int pF = lane - pA;
    if (m) audioIdx[baseA[blk] + offA + pA] = row;
    else   fusedIdx[baseF[blk] + offF + pF] = row;
}

// Build Bta[c][k]=Wa[k][c] (k<256); Btf[c][k]: k<256 -> Wf[k][c],
// k in [256,768) -> (W_v @ W_f_bot)[k-256][c]. Block 1024 computes c_f.
__global__ void k_prep(const float* __restrict__ Wa, const float* __restrict__ Wf,
                       const float* __restrict__ Wv, const float* __restrict__ bv,
                       const float* __restrict__ bf_, ushort* __restrict__ Bta,
                       ushort* __restrict__ Btf, float* __restrict__ cf) {
    int c = threadIdx.x;
    int b = blockIdx.x;
    if (b < 256) {
        Bta[(size_t)c * 256 + b] = f2bf(Wa[b * 256 + c]);
    } else if (b < 512) {
        Btf[(size_t)c * 768 + (b - 256)] = f2bf(Wf[(b - 256) * 256 + c]);
    } else if (b < 1024) {
        const float* wr = Wv + (b - 512) * 256;
        float acc = 0.f;
        for (int j = 0; j < 256; ++j) acc += wr[j] * Wf[(256 + j) * 256 + c];
        Btf[(size_t)c * 768 + 256 + (b - 512)] = f2bf(acc);
    } else {
        float acc = bf_[c];
        for (int j = 0; j < 256; ++j) acc += bv[j] * Wf[(256 + j) * 256 + c];
        cf[c] = acc;
    }
}

// Role-split GEMM. Fused blocks: sim prologue + (sim*a_in)@Wf_top + v_in@Wvf
// (K=768). Audio blocks: a_in@Wa (K=256). BM=128, BN=256, BK=64, 8 waves 2x4.
// A+B staged in LDS (round-3 scheme), gathered rows via idx arrays.
__global__ __launch_bounds__(512, 4) void k_main(
    const float* __restrict__ x, const int* __restrict__ meta,
    const int* __restrict__ fusedIdx, const int* __restrict__ audioIdx,
    const ushort* __restrict__ Bta, const ushort* __restrict__ Btf,
    const float* __restrict__ ba, const float* __restrict__ cf,
    ushort* __restrict__ gf, float* __restrict__ bn_s, float* __restrict__ bn_q)
{
    __shared__ bf16x8 As8[128 * 8];           // 16 KB
    __shared__ bf16x8 Bs8[256 * 8];           // 32 KB
    __shared__ int ridxS[128];
    __shared__ float simS[128];
    __shared__ unsigned char validS[128];
    __shared__ float redS[256], redQ[256];

    const int tid = threadIdx.x;
    const int cntF = meta[1], cntA = meta[2];
    const int nbF = (cntF + 127) >> 7;
    const int nbA = (cntA + 127) >> 7;
    const int b = blockIdx.x;
    const bool isF = b < nbF;
    const int bb = isF ? b : b - nbF;

    if (!isF && bb >= nbA) {   // idle block: zero BN slots
        if (tid < 256) {
            bn_s[(size_t)b * 256 + tid] = 0.f;
            bn_q[(size_t)b * 256 + tid] = 0.f;
        }
        return;
    }

    const int cnt = isF ? cntF : cntA;
    const int* idxArr = isF ? fusedIdx : audioIdx;
    const int lane = tid & 63;
    const int w = tid >> 6, wr = w >> 2, wc = w & 3;
    const int fr = lane & 15, fg = lane >> 4;

    if (tid < 128) {
        int gpos = bb * 128 + tid;
        int ok = gpos < cnt;
        ridxS[tid] = ok ? idxArr[gpos] : 0;
        validS[tid] = ok;
        if (!isF) simS[tid] = 1.f;
    }
    __syncthreads();

    // ---- sim prologue (fused blocks only): wave-per-row ----
    if (isF) {
        #pragma unroll 2
        for (int rr = 0; rr < 16; ++rr) {
            int r = w * 16 + rr;
            const float4* p = (const float4*)(x + (size_t)ridxS[r] * 2048 + 1024);
            float4 a0 = p[lane], a1 = p[lane + 64];
            float4 v0 = p[lane + 128], v1 = p[lane + 192];
            float dot = a0.x * v0.x + a0.y * v0.y + a0.z * v0.z + a0.w * v0.w
                      + a1.x * v1.x + a1.y * v1.y + a1.z * v1.z + a1.w * v1.w;
            float na = a0.x * a0.x + a0.y * a0.y + a0.z * a0.z + a0.w * a0.w
                     + a1.x * a1.x + a1.y * a1.y + a1.z * a1.z + a1.w * a1.w;
            float nv = v0.x * v0.x + v0.y * v0.y + v0.z * v0.z + v0.w * v0.w
                     + v1.x * v1.x + v1.y * v1.y + v1.z * v1.z + v1.w * v1.w;
            #pragma unroll
            for (int off = 32; off; off >>= 1) {
                dot += __shfl_xor(dot, off);
                na  += __shfl_xor(na,  off);
                nv  += __shfl_xor(nv,  off);
            }
            if (lane == 0)
                simS[r] = dot / fmaxf(sqrtf(na) * sqrtf(nv), 1e-8f);
        }
        __syncthreads();
    }

    // ---- GEMM ----
    const int NS = isF ? 12 : 4;
    const int kstr = isF ? 768 : 256;
    const ushort* Bp = isF ? Btf : Bta;

    const int sr = tid >> 2, sk = tid & 3;
    const float* xrow = x + (size_t)ridxS[sr] * 2048;
    const float sA = validS[sr] ? (isF ? simS[sr] : 1.f) : 0.f;
    const float sV = validS[sr] ? 1.f : 0.f;

    const int br = tid >> 1, bs = tid & 1;
    const ushort* brow = Bp + (size_t)br * kstr + bs * 32;

    f32x4 acc[4][4];
    #pragma unroll
    for (int m = 0; m < 4; ++m)
        #pragma unroll
        for (int n = 0; n < 4; ++n) acc[m][n] = (f32x4){0.f, 0.f, 0.f, 0.f};

    int4 pA[2], pB[4];
    auto loadA = [&](int st) {
        const float scl = (isF && st < 4) ? sA : (isF ? sV : sA);
        const int off = isF ? ((st < 4) ? st * 64 : 512 + (st - 4) * 64) : st * 64;
        const float4* src = (const float4*)(xrow + off + sk * 16);
        #pragma unroll
        for (int s = 0; s < 2; ++s) {
            float4 u0 = src[2 * s], u1 = src[2 * s + 1];
            int4 p;
            p.x = pk2(u0.x * scl, u0.y * scl);
            p.y = pk2(u0.z * scl, u0.w * scl);
            p.z = pk2(u1.x * scl, u1.y * scl);
            p.w = pk2(u1.z * scl, u1.w * scl);
            pA[s] = p;
        }
    };
    auto loadB = [&](int st) {
        const int4* src = (const int4*)(brow + st * 64);
        #pragma unroll
        for (int s = 0; s < 4; ++s) pB[s] = src[s];
    };

    loadA(0);
    loadB(0);

    for (int st = 0; st < NS; ++st) {
        __syncthreads();
        #pragma unroll
        for (int s = 0; s < 2; ++s)
            As8[sr * 8 + ((sk * 2 + s) ^ (sr & 7))] = __builtin_bit_cast(bf16x8, pA[s]);
        #pragma unroll
        for (int s = 0; s < 4; ++s)
            Bs8[br * 8 + ((bs * 4 + s) ^ (br & 7))] = __builtin_bit_cast(bf16x8, pB[s]);
        __syncthreads();
        if (st + 1 < NS) { loadA(st + 1); loadB(st + 1); }
        #pragma unroll
        for (int kk = 0; kk < 2; ++kk) {
            bf16x8 af[4], bfv[4];
            #pragma unroll
            for (int m = 0; m < 4; ++m) {
                int r = wr * 64 + m * 16 + fr;
                af[m] = As8[r * 8 + ((kk * 4 + fg) ^ (r & 7))];
            }
            #pragma unroll
            for (int n = 0; n < 4; ++n) {
                int c = wc * 64 + n * 16 + fr;
                bfv[n] = Bs8[c * 8 + ((kk * 4 + fg) ^ (c & 7))];
            }
            #pragma unroll
            for (int n = 0; n < 4; ++n)
                #pragma unroll
                for (int m = 0; m < 4; ++m)
                    acc[m][n] = __builtin_amdgcn_mfma_f32_16x16x32_bf16(
                        af[m], bfv[n], acc[m][n], 0, 0, 0);
        }
    }

    // ---- epilogue: bias, bf16 gf scatter, BN partials ----
    __syncthreads();
    if (tid < 256) { redS[tid] = 0.f; redQ[tid] = 0.f; }
    __syncthreads();

    const int colLo = wc * 64 + fr;
    const float* biasp = isF ? cf : ba;
    float bN[4];
    #pragma unroll
    for (int n = 0; n < 4; ++n) bN[n] = biasp[colLo + n * 16];

    float cs[4] = {0.f, 0.f, 0.f, 0.f}, cq[4] = {0.f, 0.f, 0.f, 0.f};
    #pragma unroll
    for (int m = 0; m < 4; ++m) {
        #pragma unroll
        for (int j = 0; j < 4; ++j) {
            int rloc = wr * 64 + m * 16 + fg * 4 + j;
            if (!validS[rloc]) continue;
            ushort* grow = gf + (size_t)ridxS[rloc] * 256;
            #pragma unroll
            for (int n = 0; n < 4; ++n) {
                float g = acc[m][n][j] + bN[n];
                grow[colLo + n * 16] = f2bf(g);
                cs[n] += g;
                cq[n] += g * g;
            }
        }
    }
    #pragma unroll
    for (int n = 0; n < 4; ++n) {
        atomicAdd(&redS[colLo + n * 16], cs[n]);
        atomicAdd(&redQ[colLo + n * 16], cq[n]);
    }
    __syncthreads();
    if (tid < 256) {
        bn_s[(size_t)b * 256 + tid] = redS[tid];
        bn_q[(size_t)b * 256 + tid] = redQ[tid];
    }
}

// Finalize BN stats: one block per channel, reduce 1025 block partials.
__global__ void k_stats(const float* __restrict__ bn_s, const float* __restrict__ bn_q,
                        const float* __restrict__ gamma, const float* __restrict__ beta,
                        float* __restrict__ scale, float* __restrict__ shift) {
    int c = blockIdx.x;
    int t = threadIdx.x;
    float s = 0.f, q = 0.f;
    for (int r = t; r < 1025; r += 256) {
        s += bn_s[(size_t)r * 256 + c];
        q += bn_q[(size_t)r * 256 + c];
    }
    __shared__ float ss[256], qq[256];
    ss[t] = s; qq[t] = q;
    __syncthreads();
    for (int off = 128; off; off >>= 1) {
        if (t < off) { ss[t] += ss[t + off]; qq[t] += qq[t + off]; }
        __syncthreads();
    }
    if (t == 0) {
        float mu  = ss[0] / 131072.f;
        float var = qq[0] / 131072.f - mu * mu;
        float sc = gamma[c] * rsqrtf(var + 1e-5f);
        scale[c] = sc;
        shift[c] = beta[c] - mu * sc;
    }
}

// Normalize + ReLU + 256->2 FC. One wave per row, bf16 gf input.
__global__ void k_out(const ushort* __restrict__ gf, const float* __restrict__ scale,
                      const float* __restrict__ shift, const float* __restrict__ Wfc,
                      const float* __restrict__ bfc, float* __restrict__ out) {
    int wid = threadIdx.x >> 6;
    int lane = threadIdx.x & 63;
    int i = blockIdx.x * 4 + wid;
    uint2 gv = ((const uint2*)(gf + (size_t)i * 256))[lane];
    float g0 = __uint_as_float(gv.x << 16);
    float g1 = __uint_as_float(gv.x & 0xFFFF0000u);
    float g2 = __uint_as_float(gv.y << 16);
    float g3 = __uint_as_float(gv.y & 0xFFFF0000u);
    int c0 = lane * 4;
    float4 sc = *(const float4*)(scale + c0);
    float4 sh = *(const float4*)(shift + c0);
    float y0 = fmaxf(g0 * sc.x + sh.x, 0.f);
    float y1 = fmaxf(g1 * sc.y + sh.y, 0.f);
    float y2 = fmaxf(g2 * sc.z + sh.z, 0.f);
    float y3 = fmaxf(g3 * sc.w + sh.w, 0.f);
    const float4* w = (const float4*)(Wfc + c0 * 2);
    float4 w0 = w[0], w1 = w[1];
    float p0 = y0 * w0.x + y1 * w0.z + y2 * w1.x + y3 * w1.z;
    float p1 = y0 * w0.y + y1 * w0.w + y2 * w1.y + y3 * w1.w;
    #pragma unroll
    for (int off = 32; off; off >>= 1) {
        p0 += __shfl_xor(p0, off);
        p1 += __shfl_xor(p1, off);
    }
    if (lane == 0) {
        out[(size_t)i * 2]     = p0 + bfc[0];
        out[(size_t)i * 2 + 1] = p1 + bfc[1];
    }
}

extern "C" void kernel_launch(void* const* d_in, const int* in_sizes, int n_in,
                              void* d_out, int out_size, void* d_ws, size_t ws_size,
                              hipStream_t stream) {
    const float* x          = (const float*)d_in[0];
    const unsigned char* mk = (const unsigned char*)d_in[1];
    const float* Wa  = (const float*)d_in[2];
    const float* ba  = (const float*)d_in[3];
    const float* Wv  = (const float*)d_in[4];
    const float* bv  = (const float*)d_in[5];
    const float* Wf  = (const float*)d_in[6];
    const float* bf  = (const float*)d_in[7];
    const float* gamma = (const float*)d_in[8];
    const float* beta  = (const float*)d_in[9];
    const float* Wfc = (const float*)d_in[10];
    const float* bfc = (const float*)d_in[11];
    float* out = (float*)d_out;

    char* ws = (char*)d_ws;
    int*    meta   = (int*)ws;                       // flag, cntF, cntA
    float*  scale  = (float*)(ws + 1024);
    float*  shift  = (float*)(ws + 2048);
    float*  cf     = (float*)(ws + 3072);
    int*    cntM   = (int*)(ws + 8192);
    int*    baseA  = (int*)(ws + 12288);
    int*    baseF  = (int*)(ws + 16384);
    ushort* Bta    = (ushort*)(ws + 32768);
    ushort* Btf    = (ushort*)(ws + 262144);
    int*    fusedIdx = (int*)(ws + (1u << 20));
    int*    audioIdx = (int*)(ws + (1u << 20) + (512u << 10));
    float*  bn_s   = (float*)(ws + (2u << 20));
    float*  bn_q   = (float*)(ws + (4u << 20));
    ushort* gf     = (ushort*)(ws + (8u << 20));

    int n = in_sizes[1];  // NN

    k_detect<<<1, 256, 0, stream>>>(mk, n, meta);
    k_count<<<512, 256, 0, stream>>>(mk, meta, cntM);
    k_scan<<<1, 512, 0, stream>>>(cntM, meta, baseA, baseF);
    k_fill<<<512, 256, 0, stream>>>(mk, meta, baseA, baseF, audioIdx, fusedIdx);
    k_prep<<<1025, 256, 0, stream>>>(Wa, Wf, Wv, bv, bf, Bta, Btf, cf);
    k_main<<<1025, 512, 0, stream>>>(x, meta, fusedIdx, audioIdx, Bta, Btf, ba, cf,
                                     gf, bn_s, bn_q);
    k_stats<<<256, 256, 0, stream>>>(bn_s, bn_q, gamma, beta, scale, shift);
    k_out<<<NN / 4, 256, 0, stream>>>(gf, scale, shift, Wfc, bfc, out);
}

// Round 6
// 244.265 us; speedup vs baseline: 1.6928x; 1.0803x over previous
//
#include <hip/hip_runtime.h>
#include <hip/hip_bf16.h>
#include <stdint.h>

#define NN 131072

typedef unsigned int uint;
typedef unsigned short ushort;
typedef __attribute__((ext_vector_type(8))) __bf16 bf16x8;
typedef __attribute__((ext_vector_type(2))) __bf16 bf16x2;
typedef __attribute__((ext_vector_type(4))) float f32x4;

// ---------------- ws layout (bytes) ----------------
// 0: meta (flag, cntF, cntA)
// 1K: scale(256f), 2K: shift(256f), 3K: cf(256f)
// 8K: cntM[512], 12K: baseA[512], 16K: baseF[512]
// 32K: Bwa packed (256 cols x K=256 bf16) = 128KB
// 256K: Bwf packed (256 cols x K=768 bf16) = 384KB   [k<512: Wvf, k>=512: Wf_top]
// 1M: fusedIdx (512KB), 1.5M: audioIdx (512KB)
// 2M: bn_s (1025*256 f32), 4M: bn_q
// 8M: gf bf16 (NN*256)

__device__ __forceinline__ ushort f2bf(float f) {
    uint u = __float_as_uint(f);
    u += 0x7FFF + ((u >> 16) & 1);
    return (ushort)(u >> 16);
}
__device__ __forceinline__ uint pk2(float a, float b) {
    bf16x2 t;
    t[0] = (__bf16)a;
    t[1] = (__bf16)b;
    return __builtin_bit_cast(uint, t);
}
__device__ __forceinline__ bool mask_val(const unsigned char* m8, int flag, int i) {
    return flag ? (m8[(size_t)i * 4] != 0) : (m8[i] != 0);
}
// Packed B layout: fragment chunk (kb = k>>5, ct = c>>4) is 512 contiguous
// ushorts in exact MFMA-lane order: lane = fg*16+fr, elem = k&7.
__device__ __forceinline__ size_t pack_off(int k, int c) {
    return (size_t)(((k >> 5) * 16 + (c >> 4)) * 512
                    + (((k >> 3) & 3) * 16 + (c & 15)) * 8 + (k & 7));
}

// Detect whether mask buffer is 1-byte bool (flag=0) or int32 (flag=1).
// Scans byte offsets ===1 (mod 4) over the first n bytes (safe for both).
__global__ void k_detect(const uint* m32, int n, int* flag) {
    __shared__ int cnt;
    if (threadIdx.x == 0) cnt = 0;
    __syncthreads();
    int local = 0;
    int nw = n >> 2;
    for (int i = threadIdx.x; i < nw; i += 1024)
        if (m32[i] & 0x0000FF00u) local = 1;
    if (local) atomicAdd(&cnt, 1);
    __syncthreads();
    if (threadIdx.x == 0) *flag = (cnt == 0) ? 1 : 0;
}

// Per-256-row-chunk audio count.
__global__ void k_count(const unsigned char* m8, const int* flagp, int* cntM) {
    int flag = *flagp;
    int t = threadIdx.x;
    bool m = mask_val(m8, flag, blockIdx.x * 256 + t);
    unsigned long long bal = __ballot(m);
    __shared__ int wsum[4];
    if ((t & 63) == 0) wsum[t >> 6] = __popcll(bal);
    __syncthreads();
    if (t == 0) cntM[blockIdx.x] = wsum[0] + wsum[1] + wsum[2] + wsum[3];
}

// Exclusive scan of chunk counts -> bases + totals. One block, 512 threads.
__global__ void k_scan(const int* __restrict__ cntM, int* __restrict__ meta,
                       int* __restrict__ baseA, int* __restrict__ baseF) {
    __shared__ int sA[512], sF[512];
    int t = threadIdx.x;
    int a = cntM[t], f = 256 - a;
    sA[t] = a; sF[t] = f;
    __syncthreads();
    for (int off = 1; off < 512; off <<= 1) {
        int va = (t >= off) ? sA[t - off] : 0;
        int vf = (t >= off) ? sF[t - off] : 0;
        __syncthreads();
        sA[t] += va; sF[t] += vf;
        __syncthreads();
    }
    baseA[t] = sA[t] - a;
    baseF[t] = sF[t] - f;
    if (t == 511) { meta[2] = sA[511]; meta[1] = sF[511]; }
}

// Stable partition fill.
__global__ void k_fill(const unsigned char* m8, const int* flagp,
                       const int* __restrict__ baseA, const int* __restrict__ baseF,
                       int* __restrict__ audioIdx, int* __restrict__ fusedIdx) {
    int flag = *flagp;
    int blk = blockIdx.x, t = threadIdx.x;
    int row = blk * 256 + t;
    bool m = mask_val(m8, flag, row);
    unsigned long long bal = __ballot(m);
    int lane = t & 63, w = t >> 6;
    unsigned long long lt = (1ull << lane) - 1ull;
    int pA = __popcll(bal & lt);
    __shared__ int wA[4];
    if (lane == 0) wA[w] = __popcll(bal);
    __syncthreads();
    int offA = 0;
    for (int i = 0; i < w; ++i) offA += wA[i];
    int offF = w * 64 - offA;
    int pF = lane - pA;
    if (m) audioIdx[baseA[blk] + offA + pA] = row;
    else   fusedIdx[baseF[blk] + offF + pF] = row;
}

// Build packed weights. Bwa: k<256 -> Wa[k][c].
// Bwf (fused, K=768, order [v_in|a_in]): k<512 -> (Wv@Wf_bot)[k][c];
// k in [512,768) -> Wf[k-512][c]. Block 1024 computes c_f.
__global__ void k_prep(const float* __restrict__ Wa, const float* __restrict__ Wf,
                       const float* __restrict__ Wv, const float* __restrict__ bv,
                       const float* __restrict__ bf_, ushort* __restrict__ Bwa,
                       ushort* __restrict__ Bwf, float* __restrict__ cf) {
    int c = threadIdx.x;
    int b = blockIdx.x;
    if (b < 256) {
        Bwa[pack_off(b, c)] = f2bf(Wa[b * 256 + c]);
    } else if (b < 512) {
        Bwf[pack_off(512 + (b - 256), c)] = f2bf(Wf[(b - 256) * 256 + c]);
    } else if (b < 1024) {
        int k = b - 512;
        const float* wr = Wv + k * 256;
        float acc = 0.f;
        for (int j = 0; j < 256; ++j) acc += wr[j] * Wf[(256 + j) * 256 + c];
        Bwf[pack_off(k, c)] = f2bf(acc);
    } else {
        float acc = bf_[c];
        for (int j = 0; j < 256; ++j) acc += bv[j] * Wf[(256 + j) * 256 + c];
        cf[c] = acc;
    }
}

// Role-split GEMM. Fused blocks: sim prologue + v_in@Wvf + (sim*a_in)@Wf_top
// (K=768, v_in first so step 0 overlaps sim). Audio: a_in@Wa (K=256).
// BM=128, BN=256, BK=64, 8 waves 2x4. A double-buffered in LDS (1 barrier
// per step); B-fragments read directly from L2 via packed coalesced layout.
__global__ __launch_bounds__(512, 4) void k_main(
    const float* __restrict__ x, const int* __restrict__ meta,
    const int* __restrict__ fusedIdx, const int* __restrict__ audioIdx,
    const ushort* __restrict__ Bwa, const ushort* __restrict__ Bwf,
    const float* __restrict__ ba, const float* __restrict__ cf,
    ushort* __restrict__ gf, float* __restrict__ bn_s, float* __restrict__ bn_q)
{
    __shared__ bf16x8 As8[2][128 * 8];        // 2 x 16 KB
    __shared__ int ridxS[128];
    __shared__ float simS[128];
    __shared__ unsigned char validS[128];
    __shared__ float redS[256], redQ[256];

    const int tid = threadIdx.x;
    const int cntF = meta[1], cntA = meta[2];
    const int nbF = (cntF + 127) >> 7;
    const int nbA = (cntA + 127) >> 7;
    const int b = blockIdx.x;
    const bool isF = b < nbF;
    const int bb = isF ? b : b - nbF;

    if (!isF && bb >= nbA) {   // idle block: zero BN slots
        if (tid < 256) {
            bn_s[(size_t)b * 256 + tid] = 0.f;
            bn_q[(size_t)b * 256 + tid] = 0.f;
        }
        return;
    }

    const int cnt = isF ? cntF : cntA;
    const int* idxArr = isF ? fusedIdx : audioIdx;
    const int lane = tid & 63;
    const int w = tid >> 6, wr = w >> 2, wc = w & 3;
    const int fr = lane & 15, fg = lane >> 4;

    if (tid < 128) {
        int gpos = bb * 128 + tid;
        int ok = gpos < cnt;
        ridxS[tid] = ok ? idxArr[gpos] : 0;
        validS[tid] = ok;
        simS[tid] = 1.f;
    }
    __syncthreads();

    const int NS = isF ? 12 : 4;
    const int sr = tid >> 2, sk = tid & 3;
    const float* xrow = x + (size_t)ridxS[sr] * 2048;
    const float sVf = validS[sr] ? 1.f : 0.f;
    float sAf = 0.f;   // set after sim phase

    int4 pA[2];
    auto loadA = [&](int st) {
        const float scl = (isF && st >= 8) ? sAf : sVf;
        const int off = isF ? ((st < 8) ? 512 + st * 64 : (st - 8) * 64) : st * 64;
        const float4* src = (const float4*)(xrow + off + sk * 16);
        #pragma unroll
        for (int s = 0; s < 2; ++s) {
            float4 u0 = src[2 * s], u1 = src[2 * s + 1];
            int4 p;
            p.x = pk2(u0.x * scl, u0.y * scl);
            p.y = pk2(u0.z * scl, u0.w * scl);
            p.z = pk2(u1.x * scl, u1.y * scl);
            p.w = pk2(u1.z * scl, u1.w * scl);
            pA[s] = p;
        }
    };
    auto storeA = [&](int buf) {
        #pragma unroll
        for (int s = 0; s < 2; ++s)
            As8[buf][sr * 8 + ((sk * 2 + s) ^ (sr & 7))] = __builtin_bit_cast(bf16x8, pA[s]);
    };

    // step 0 (v_in / a_in-audio): sim-independent -> issue before sim phase
    loadA(0);

    // ---- sim prologue (fused blocks only): wave-per-row coalesced ----
    if (isF) {
        #pragma unroll 2
        for (int rr = 0; rr < 16; ++rr) {
            int r = w * 16 + rr;
            const float4* p = (const float4*)(x + (size_t)ridxS[r] * 2048 + 1024);
            float4 a0 = p[lane], a1 = p[lane + 64];
            float4 v0 = p[lane + 128], v1 = p[lane + 192];
            float dot = a0.x * v0.x + a0.y * v0.y + a0.z * v0.z + a0.w * v0.w
                      + a1.x * v1.x + a1.y * v1.y + a1.z * v1.z + a1.w * v1.w;
            float na = a0.x * a0.x + a0.y * a0.y + a0.z * a0.z + a0.w * a0.w
                     + a1.x * a1.x + a1.y * a1.y + a1.z * a1.z + a1.w * a1.w;
            float nv = v0.x * v0.x + v0.y * v0.y + v0.z * v0.z + v0.w * v0.w
                     + v1.x * v1.x + v1.y * v1.y + v1.z * v1.z + v1.w * v1.w;
            #pragma unroll
            for (int off = 32; off; off >>= 1) {
                dot += __shfl_xor(dot, off);
                na  += __shfl_xor(na,  off);
                nv  += __shfl_xor(nv,  off);
            }
            if (lane == 0)
                simS[r] = dot / fmaxf(sqrtf(na) * sqrtf(nv), 1e-8f);
        }
    }
    __syncthreads();
    sAf = validS[sr] ? simS[sr] : 0.f;

    // ---- GEMM: A dbuf LDS, B direct from packed L2-resident buffers ----
    const ushort* bBase = (isF ? Bwf : Bwa) + ((size_t)(wc * 4) << 9) + (lane << 3);

    f32x4 acc[4][4];
    #pragma unroll
    for (int m = 0; m < 4; ++m)
        #pragma unroll
        for (int n = 0; n < 4; ++n) acc[m][n] = (f32x4){0.f, 0.f, 0.f, 0.f};

    storeA(0);
    __syncthreads();

    for (int st = 0; st < NS; ++st) {
        if (st + 1 < NS) loadA(st + 1);
        const int buf = st & 1;
        #pragma unroll
        for (int kk = 0; kk < 2; ++kk) {
            bf16x8 bv[4], af[4];
            #pragma unroll
            for (int n = 0; n < 4; ++n)
                bv[n] = *(const bf16x8*)(bBase + ((size_t)((st * 2 + kk) * 16 + n) << 9));
            #pragma unroll
            for (int m = 0; m < 4; ++m) {
                int r = wr * 64 + m * 16 + fr;
                af[m] = As8[buf][r * 8 + ((kk * 4 + fg) ^ (r & 7))];
            }
            #pragma unroll
            for (int n = 0; n < 4; ++n)
                #pragma unroll
                for (int m = 0; m < 4; ++m)
                    acc[m][n] = __builtin_amdgcn_mfma_f32_16x16x32_bf16(
                        af[m], bv[n], acc[m][n], 0, 0, 0);
        }
        if (st + 1 < NS) storeA((st + 1) & 1);
        __syncthreads();
    }

    // ---- epilogue: bias, bf16 gf scatter, BN partials ----
    if (tid < 256) { redS[tid] = 0.f; redQ[tid] = 0.f; }
    __syncthreads();

    const int colLo = wc * 64 + fr;
    const float* biasp = isF ? cf : ba;
    float bN[4];
    #pragma unroll
    for (int n = 0; n < 4; ++n) bN[n] = biasp[colLo + n * 16];

    float cs[4] = {0.f, 0.f, 0.f, 0.f}, cq[4] = {0.f, 0.f, 0.f, 0.f};
    #pragma unroll
    for (int m = 0; m < 4; ++m) {
        #pragma unroll
        for (int j = 0; j < 4; ++j) {
            int rloc = wr * 64 + m * 16 + fg * 4 + j;
            if (!validS[rloc]) continue;
            ushort* grow = gf + (size_t)ridxS[rloc] * 256;
            #pragma unroll
            for (int n = 0; n < 4; ++n) {
                float g = acc[m][n][j] + bN[n];
                grow[colLo + n * 16] = f2bf(g);
                cs[n] += g;
                cq[n] += g * g;
            }
        }
    }
    #pragma unroll
    for (int n = 0; n < 4; ++n) {
        atomicAdd(&redS[colLo + n * 16], cs[n]);
        atomicAdd(&redQ[colLo + n * 16], cq[n]);
    }
    __syncthreads();
    if (tid < 256) {
        bn_s[(size_t)b * 256 + tid] = redS[tid];
        bn_q[(size_t)b * 256 + tid] = redQ[tid];
    }
}

// Finalize BN stats: one block per channel, reduce 1025 block partials.
__global__ void k_stats(const float* __restrict__ bn_s, const float* __restrict__ bn_q,
                        const float* __restrict__ gamma, const float* __restrict__ beta,
                        float* __restrict__ scale, float* __restrict__ shift) {
    int c = blockIdx.x;
    int t = threadIdx.x;
    float s = 0.f, q = 0.f;
    for (int r = t; r < 1025; r += 256) {
        s += bn_s[(size_t)r * 256 + c];
        q += bn_q[(size_t)r * 256 + c];
    }
    __shared__ float ss[256], qq[256];
    ss[t] = s; qq[t] = q;
    __syncthreads();
    for (int off = 128; off; off >>= 1) {
        if (t < off) { ss[t] += ss[t + off]; qq[t] += qq[t + off]; }
        __syncthreads();
    }
    if (t == 0) {
        float mu  = ss[0] / 131072.f;
        float var = qq[0] / 131072.f - mu * mu;
        float sc = gamma[c] * rsqrtf(var + 1e-5f);
        scale[c] = sc;
        shift[c] = beta[c] - mu * sc;
    }
}

// Normalize + ReLU + 256->2 FC. One wave per row, bf16 gf input.
__global__ void k_out(const ushort* __restrict__ gf, const float* __restrict__ scale,
                      const float* __restrict__ shift, const float* __restrict__ Wfc,
                      const float* __restrict__ bfc, float* __restrict__ out) {
    int wid = threadIdx.x >> 6;
    int lane = threadIdx.x & 63;
    int i = blockIdx.x * 4 + wid;
    uint2 gv = ((const uint2*)(gf + (size_t)i * 256))[lane];
    float g0 = __uint_as_float(gv.x << 16);
    float g1 = __uint_as_float(gv.x & 0xFFFF0000u);
    float g2 = __uint_as_float(gv.y << 16);
    float g3 = __uint_as_float(gv.y & 0xFFFF0000u);
    int c0 = lane * 4;
    float4 sc = *(const float4*)(scale + c0);
    float4 sh = *(const float4*)(shift + c0);
    float y0 = fmaxf(g0 * sc.x + sh.x, 0.f);
    float y1 = fmaxf(g1 * sc.y + sh.y, 0.f);
    float y2 = fmaxf(g2 * sc.z + sh.z, 0.f);
    float y3 = fmaxf(g3 * sc.w + sh.w, 0.f);
    const float4* w = (const float4*)(Wfc + c0 * 2);
    float4 w0 = w[0], w1 = w[1];
    float p0 = y0 * w0.x + y1 * w0.z + y2 * w1.x + y3 * w1.z;
    float p1 = y0 * w0.y + y1 * w0.w + y2 * w1.y + y3 * w1.w;
    #pragma unroll
    for (int off = 32; off; off >>= 1) {
        p0 += __shfl_xor(p0, off);
        p1 += __shfl_xor(p1, off);
    }
    if (lane == 0) {
        out[(size_t)i * 2]     = p0 + bfc[0];
        out[(size_t)i * 2 + 1] = p1 + bfc[1];
    }
}

extern "C" void kernel_launch(void* const* d_in, const int* in_sizes, int n_in,
                              void* d_out, int out_size, void* d_ws, size_t ws_size,
                              hipStream_t stream) {
    const float* x          = (const float*)d_in[0];
    const unsigned char* mk = (const unsigned char*)d_in[1];
    const float* Wa  = (const float*)d_in[2];
    const float* ba  = (const float*)d_in[3];
    const float* Wv  = (const float*)d_in[4];
    const float* bv  = (const float*)d_in[5];
    const float* Wf  = (const float*)d_in[6];
    const float* bf  = (const float*)d_in[7];
    const float* gamma = (const float*)d_in[8];
    const float* beta  = (const float*)d_in[9];
    const float* Wfc = (const float*)d_in[10];
    const float* bfc = (const float*)d_in[11];
    float* out = (float*)d_out;

    char* ws = (char*)d_ws;
    int*    meta   = (int*)ws;                       // flag, cntF, cntA
    float*  scale  = (float*)(ws + 1024);
    float*  shift  = (float*)(ws + 2048);
    float*  cf     = (float*)(ws + 3072);
    int*    cntM   = (int*)(ws + 8192);
    int*    baseA  = (int*)(ws + 12288);
    int*    baseF  = (int*)(ws + 16384);
    ushort* Bwa    = (ushort*)(ws + 32768);
    ushort* Bwf    = (ushort*)(ws + 262144);
    int*    fusedIdx = (int*)(ws + (1u << 20));
    int*    audioIdx = (int*)(ws + (1u << 20) + (512u << 10));
    float*  bn_s   = (float*)(ws + (2u << 20));
    float*  bn_q   = (float*)(ws + (4u << 20));
    ushort* gf     = (ushort*)(ws + (8u << 20));

    int n = in_sizes[1];  // NN

    k_detect<<<1, 1024, 0, stream>>>((const uint*)mk, n, meta);
    k_count<<<512, 256, 0, stream>>>(mk, meta, cntM);
    k_scan<<<1, 512, 0, stream>>>(cntM, meta, baseA, baseF);
    k_fill<<<512, 256, 0, stream>>>(mk, meta, baseA, baseF, audioIdx, fusedIdx);
    k_prep<<<1025, 256, 0, stream>>>(Wa, Wf, Wv, bv, bf, Bwa, Bwf, cf);
    k_main<<<1025, 512, 0, stream>>>(x, meta, fusedIdx, audioIdx, Bwa, Bwf, ba, cf,
                                     gf, bn_s, bn_q);
    k_stats<<<256, 256, 0, stream>>>(bn_s, bn_q, gamma, beta, scale, shift);
    k_out<<<NN / 4, 256, 0, stream>>>(gf, scale, shift, Wfc, bfc, out);
}